// Round 1
// baseline (567.792 us; speedup 1.0000x reference)
//
#include <hip/hip_runtime.h>
#include <hip/hip_bf16.h>
#include <math.h>

#define SS   16
#define NN   1024
#define RR   4
#define CINC 128
#define COUTC 128
#define RP1  5
#define EPSF 1e-7f

typedef __bf16 bf16x8 __attribute__((ext_vector_type(8)));
typedef __bf16 bf16x4 __attribute__((ext_vector_type(4)));
typedef float  f32x4  __attribute__((ext_vector_type(4)));

// Workspace layout:
//   Yt : bf16 [S][R][COUT][N]   (Y_c = X_s @ W_c, stored b-major for direct B-frag loads)
//        = 16*4*128*1024 elems  = 16 MiB
//   Z  : f32  [S][N][COUT]      (X_s @ theta) = 8 MiB, at byte offset 16 MiB
#define YT_BYTES ((size_t)SS * RR * COUTC * NN * 2)

// ---------------------------------------------------------------------------
// Stage 1: Yt[s][c][b][j] = bf16( sum_a x[s][j][a] * weight[a][b][c] )   (c<4)
//          Z [s][j][b]    =       sum_a x[s][j][a] * theta[a][b]        (ch==4)
// grid = 16 s * 5 ch * 16 j-tiles(64) = 1280 blocks, 256 thr
// ---------------------------------------------------------------------------
__global__ __launch_bounds__(256) void prep_kernel(
    const float* __restrict__ x, const float* __restrict__ weight,
    const float* __restrict__ theta, __bf16* __restrict__ Yt,
    float* __restrict__ Z)
{
    const int bx = blockIdx.x;
    const int it = bx & 15;            // 64-row token tile
    const int ch = (bx >> 4) % 5;
    const int s  = (bx >> 4) / 5;

    __shared__ __bf16 lx[64 * 136];    // [token_row][a], pad 136 (68 dw = 4 mod 32: conflict-free)
    __shared__ __bf16 lw[128 * 136];   // [b][a] (transposed weight slice)

    const int t = threadIdx.x;
    {   // X tile -> LDS bf16
        const int i = t >> 2, q = t & 3;
        const float* xrow = x + ((size_t)s * NN + it * 64 + i) * CINC;
#pragma unroll
        for (int k = 0; k < 8; ++k) {
            f32x4 v = *(const f32x4*)(xrow + q * 32 + k * 4);
            bf16x4 b; b[0] = (__bf16)v.x; b[1] = (__bf16)v.y; b[2] = (__bf16)v.z; b[3] = (__bf16)v.w;
            *(bf16x4*)&lx[i * 136 + q * 32 + k * 4] = b;
        }
    }
    {   // W slice (transposed) -> LDS bf16
        const int b = t >> 1, h = t & 1;
        if (ch < 4) {
#pragma unroll
            for (int k = 0; k < 64; ++k) {
                const int a = h * 64 + k;
                lw[b * 136 + a] = (__bf16)weight[(a * COUTC + b) * RR + ch];
            }
        } else {
#pragma unroll
            for (int k = 0; k < 64; ++k) {
                const int a = h * 64 + k;
                lw[b * 136 + a] = (__bf16)theta[a * COUTC + b];
            }
        }
    }
    __syncthreads();

    const int lane = t & 63, w = t >> 6;
    const int m16 = lane & 15, quad = lane >> 4;

    f32x4 acc[8];
#pragma unroll
    for (int i = 0; i < 8; ++i) acc[i] = (f32x4){0.f, 0.f, 0.f, 0.f};

#pragma unroll
    for (int k0 = 0; k0 < CINC; k0 += 32) {
        const bf16x8 af = *(const bf16x8*)&lx[(w * 16 + m16) * 136 + k0 + quad * 8];
#pragma unroll
        for (int bs = 0; bs < 8; ++bs) {
            const bf16x8 bf = *(const bf16x8*)&lw[(bs * 16 + m16) * 136 + k0 + quad * 8];
            acc[bs] = __builtin_amdgcn_mfma_f32_16x16x32_bf16(af, bf, acc[bs], 0, 0, 0);
        }
    }

    const int j0 = it * 64 + w * 16 + quad * 4;  // token row base for this lane's C rows
    if (ch < 4) {
#pragma unroll
        for (int bs = 0; bs < 8; ++bs) {
            const int b = bs * 16 + m16;
            __bf16* p = Yt + (((size_t)(s * 4 + ch) * COUTC + b) * NN + j0);
            bf16x4 v; v[0] = (__bf16)acc[bs][0]; v[1] = (__bf16)acc[bs][1];
                      v[2] = (__bf16)acc[bs][2]; v[3] = (__bf16)acc[bs][3];
            *(bf16x4*)p = v;
        }
    } else {
#pragma unroll
        for (int bs = 0; bs < 8; ++bs) {
            const int b = bs * 16 + m16;
#pragma unroll
            for (int r = 0; r < 4; ++r)
                Z[((size_t)s * NN + j0 + r) * COUTC + b] = acc[bs][r];
        }
    }
}

// ---------------------------------------------------------------------------
// Main: out[s,i,b] = tanh( Z[s,i,b] + sum_c norm[s,i,c] * sum_j Ar[s,i,j,c]*Y_c[j,b] )
// grid = 16 s * 32 i-tiles(32) = 512 blocks, 256 thr (4 waves), 2 blocks/CU.
// Wave w owns b-range [32w, 32w+32) for ALL 4 c's -> no cross-wave combine.
// ---------------------------------------------------------------------------
__global__ __launch_bounds__(256, 2) void main_kernel(
    const float* __restrict__ A, const __bf16* __restrict__ Yt,
    const float* __restrict__ Z, float* __restrict__ out)
{
    const int bx = blockIdx.x;
    const int s  = bx >> 5;
    const int i0 = (bx & 31) * 32;

    __shared__ __bf16 lA[4][32][40];   // [c][i][j], row stride 40 bf16 = 80 B (20 dw: conflict-free b128)
    __shared__ float  lnorm[4][32];

    const int t = threadIdx.x;
    const int lane = t & 63, w = t >> 6;
    const int m16 = lane & 15, quad = lane >> 4;

    const int irow = t >> 3;           // staging row 0..31
    const int q    = t & 7;            // staging j-group (4 j's each)

    // A row segment: A[s][i0+irow][j..][c], this thread reads dwords [20q, 20q+20) of each 32-j window
    const float* Ap = A + ((size_t)(s * NN + i0 + irow) * NN) * RP1 + q * 20;

    float rs[4] = {0.f, 0.f, 0.f, 0.f};
    f32x4 acc[4][2][2];
#pragma unroll
    for (int c = 0; c < 4; ++c)
#pragma unroll
        for (int is = 0; is < 2; ++is)
#pragma unroll
            for (int bs = 0; bs < 2; ++bs) acc[c][is][bs] = (f32x4){0.f, 0.f, 0.f, 0.f};

    const __bf16* Ys = Yt + (size_t)s * 4 * COUTC * NN;

    // prologue A prefetch (5 aligned dwordx4 = 4 j's x 5 channels)
    f32x4 ld[5];
#pragma unroll
    for (int u = 0; u < 5; ++u) ld[u] = __builtin_nontemporal_load((const f32x4*)Ap + u);

    for (int kk = 0; kk < 32; ++kk) {
        // B-fragments for this step, straight from global (L2/L3-resident Y)
        bf16x8 bf[4][2];
        const __bf16* yp = Ys + kk * 32 + quad * 8;
#pragma unroll
        for (int c = 0; c < 4; ++c)
#pragma unroll
            for (int bs = 0; bs < 2; ++bs)
                bf[c][bs] = *(const bf16x8*)(yp + (size_t)(c * COUTC + w * 32 + bs * 16 + m16) * NN);

        __syncthreads();   // previous step's LDS reads done

        {   // de-interleave channels, convert, stage to per-c LDS planes; fp32 row-sums
            const float v0[4] = {ld[0].x, ld[1].y, ld[2].z, ld[3].w};
            const float v1[4] = {ld[0].y, ld[1].z, ld[2].w, ld[4].x};
            const float v2[4] = {ld[0].z, ld[1].w, ld[3].x, ld[4].y};
            const float v3[4] = {ld[0].w, ld[2].x, ld[3].y, ld[4].z};
            const float* vv[4] = {v0, v1, v2, v3};
#pragma unroll
            for (int c = 0; c < 4; ++c) {
                const float* v = vv[c];
                rs[c] += v[0] + v[1] + v[2] + v[3];
                bf16x4 pk; pk[0] = (__bf16)v[0]; pk[1] = (__bf16)v[1];
                           pk[2] = (__bf16)v[2]; pk[3] = (__bf16)v[3];
                *(bf16x4*)&lA[c][irow][q * 4] = pk;
            }
        }
        __syncthreads();   // staged tile visible

        if (kk < 31) {     // prefetch next A step (stays in flight across MFMAs)
            Ap += 160;
#pragma unroll
            for (int u = 0; u < 5; ++u) ld[u] = __builtin_nontemporal_load((const f32x4*)Ap + u);
        }

#pragma unroll
        for (int c = 0; c < 4; ++c) {
            const bf16x8 af0 = *(const bf16x8*)&lA[c][m16][quad * 8];
            const bf16x8 af1 = *(const bf16x8*)&lA[c][16 + m16][quad * 8];
            acc[c][0][0] = __builtin_amdgcn_mfma_f32_16x16x32_bf16(af0, bf[c][0], acc[c][0][0], 0, 0, 0);
            acc[c][0][1] = __builtin_amdgcn_mfma_f32_16x16x32_bf16(af0, bf[c][1], acc[c][0][1], 0, 0, 0);
            acc[c][1][0] = __builtin_amdgcn_mfma_f32_16x16x32_bf16(af1, bf[c][0], acc[c][1][0], 0, 0, 0);
            acc[c][1][1] = __builtin_amdgcn_mfma_f32_16x16x32_bf16(af1, bf[c][1], acc[c][1][1], 0, 0, 0);
        }
    }

    // row-sums -> norms (8 staging lanes per row, xor-shuffle reduce)
#pragma unroll
    for (int c = 0; c < 4; ++c) {
        float v = rs[c];
        v += __shfl_xor(v, 1);
        v += __shfl_xor(v, 2);
        v += __shfl_xor(v, 4);
        if (q == 0) lnorm[c][irow] = 1.0f / (v + EPSF);
    }
    __syncthreads();

    // epilogue: combine c's with norms, add Z, tanh, store
#pragma unroll
    for (int is = 0; is < 2; ++is) {
        f32x4 nv[4];
#pragma unroll
        for (int c = 0; c < 4; ++c) nv[c] = *(const f32x4*)&lnorm[c][is * 16 + quad * 4];
        const int row0 = i0 + is * 16 + quad * 4;
#pragma unroll
        for (int bs = 0; bs < 2; ++bs) {
            const int b = w * 32 + bs * 16 + m16;
#pragma unroll
            for (int r = 0; r < 4; ++r) {
                float v = acc[0][is][bs][r] * nv[0][r]
                        + acc[1][is][bs][r] * nv[1][r]
                        + acc[2][is][bs][r] * nv[2][r]
                        + acc[3][is][bs][r] * nv[3][r];
                const size_t idx = ((size_t)s * NN + row0 + r) * COUTC + b;
                out[idx] = tanhf(v + Z[idx]);
            }
        }
    }
}

extern "C" void kernel_launch(void* const* d_in, const int* in_sizes, int n_in,
                              void* d_out, int out_size, void* d_ws, size_t ws_size,
                              hipStream_t stream)
{
    const float* A      = (const float*)d_in[0];
    const float* x      = (const float*)d_in[1];
    const float* weight = (const float*)d_in[2];
    const float* theta  = (const float*)d_in[3];
    float* out = (float*)d_out;

    __bf16* Yt = (__bf16*)d_ws;
    float*  Z  = (float*)((char*)d_ws + YT_BYTES);

    prep_kernel<<<dim3(SS * 5 * 16), dim3(256), 0, stream>>>(x, weight, theta, Yt, Z);
    main_kernel<<<dim3(SS * 32), dim3(256), 0, stream>>>(A, Yt, Z, out);
}